// Round 10
// baseline (186.660 us; speedup 1.0000x reference)
//
#include <hip/hip_runtime.h>

#define B_ 8
#define N_ 8192
#define S_ 2048
#define D_ 256
#define EPS_ 1e-8f

/* ---------------- 2-D (x,y) bin grid ---------------- */
#define NBG   32
#define NBIN  1024            /* NBG*NBG */
#define XMINB (-4.0f)
#define INVWB 4.0f            /* bin width 0.25 over [-4,4) */
#define CUMP2 1026            /* cum entries (1024+1) padded even */

/* workspace layout (bytes) */
#define WS_SID  (B_*S_*16)                 /* wpts: 262144 */
#define WS_CUM  (WS_SID + B_*S_*2)         /* wsid: +32768 = 294912 */
#define WS_QID  (WS_CUM + B_*CUMP2*2)      /* wcum: +16416 = 311328 */
#define WS_NEED (WS_QID + B_*N_*2)         /* wqid: +131072 = 442400 */

#define QW 8                               /* queries per wave (8 slots each) */
#define QBLK 32                            /* queries per 256-thr block */

/* ---------------- brute-force fallback params (proven R2 path) ----- */
#define TILE_Q 64
#define NTHR 512
#define NCH 8
#define CHUNK (S_/NCH)
#define HALF (CHUNK/2)

// Branchless stable top-3 insert (float + index) — brute fallback only.
__device__ __forceinline__ void insert3(float dd, int s,
                                        float& d0, float& d1, float& d2,
                                        int& i0, int& i1, int& i2) {
    bool ca = dd < d0;
    bool cb = dd < d1;
    bool cc = dd < d2;
    int i2n = cb ? i1 : (cc ? s : i2);
    int i1n = ca ? i0 : (cb ? s : i1);
    int i0n = ca ? s : i0;
    d2 = fminf(d2, fmaxf(d1, dd));
    d1 = __builtin_amdgcn_fmed3f(d0, d1, dd);
    d0 = fminf(d0, dd);
    i0 = i0n; i1 = i1n; i2 = i2n;
}

// Value-only top-3 insert (3 ops) — phase-1 bound probe only.
__device__ __forceinline__ void ins3v(float x, float& d0, float& d1, float& d2) {
    d2 = fminf(d2, fmaxf(d1, x));
    d1 = __builtin_amdgcn_fmed3f(d0, d1, x);
    d0 = fminf(d0, x);
}

// Top-3 insert on packed u64 composite (sortable(key)<<16 | pos).
// EMPIRICAL (R7 vs R8): u64 form is the fast AND tie-safe variant (total
// order incl. index -> multiset-exact under key ties; an equality-match
// index pass was rejected: expected ~10 tie collisions/run corrupt output).
// MERGE DISCIPLINE (R3): only combine DISJOINT sets; never re-reduce a
// merged result. Phase 2 uses fresh accumulators, per-lane slot classes
// disjoint, one destructive butterfly at the end.
__device__ __forceinline__ void ins3u64(unsigned long long x,
    unsigned long long& d0, unsigned long long& d1, unsigned long long& d2) {
    bool ca = x < d0, cb = x < d1, cc = x < d2;
    d2 = cb ? d1 : (cc ? x : d2);
    d1 = ca ? d0 : (cb ? x : d1);
    d0 = ca ? x : d0;
}

__device__ __forceinline__ unsigned long long packkey(float key, int j) {
    unsigned int kb = __float_as_uint(key);
    unsigned int sb = kb ^ ((unsigned int)((int)kb >> 31) | 0x80000000u);
    return ((unsigned long long)sb << 16) | (unsigned)j;
}

/* ------- prep: counting-sort candidates AND queries by (xb,yb) bin ----- */
// blocks 0..7: candidates of batch b -> wpts (-2bx,-2by,-2bz,|b|^2) sorted
// by 2-D bin, wsid original idx, wcum[1026] bin prefix (u16).
// blocks 8..15: queries -> wqid sorted by the same 2-D bin (wave locality).
__global__ __launch_bounds__(1024) void prep_sort_kernel(
    const float* __restrict__ xyz1, const float* __restrict__ xyz2,
    float4* __restrict__ wpts, unsigned short* __restrict__ wsid,
    unsigned short* __restrict__ wcum, unsigned short* __restrict__ wqid)
{
    __shared__ unsigned int h[NBIN];            // 4 KB
    __shared__ unsigned int wsum[16];
    __shared__ unsigned short cbuf[N_];         // 16 KB
    const int blk = blockIdx.x, t = threadIdx.x, lane = t & 63, wv = t >> 6;

    const bool isq = blk >= B_;
    const int b = isq ? blk - B_ : blk;
    const int cnt = isq ? N_ : S_;
    const float* xs = isq ? (xyz1 + (size_t)b*3*N_) : (xyz2 + (size_t)b*3*S_);

    h[t] = 0;                                   // 1024 thr cover NBIN exactly
    __syncthreads();
    for (int s = t; s < cnt; s += 1024) {
        float x = xs[s], y = xs[cnt + s];
        int xb = min(NBG-1, max(0, (int)floorf((x - XMINB) * INVWB)));
        int yb = min(NBG-1, max(0, (int)floorf((y - XMINB) * INVWB)));
        int bin = (xb << 5) | yb;
        cbuf[s] = (unsigned short)bin;
        atomicAdd(&h[bin], 1u);
    }
    __syncthreads();
    // exclusive scan of h[1024]: per-wave shfl scan + 16 partials
    unsigned int v = h[t];
    unsigned int incl = v;
    #pragma unroll
    for (int off = 1; off < 64; off <<= 1) {
        unsigned int u = __shfl_up(incl, off);
        if (lane >= off) incl += u;
    }
    if (lane == 63) wsum[wv] = incl;
    __syncthreads();
    unsigned int base = 0;
    for (int w = 0; w < wv; ++w) base += wsum[w];
    unsigned int excl = base + incl - v;
    __syncthreads();
    h[t] = excl;
    if (!isq) {
        unsigned short* cum = wcum + (size_t)b * CUMP2;
        cum[t] = (unsigned short)excl;
        if (t == 0) { cum[NBIN] = (unsigned short)S_; cum[NBIN+1] = (unsigned short)S_; }
    }
    __syncthreads();
    if (!isq) {
        for (int s = t; s < S_; s += 1024) {
            unsigned int pos = atomicAdd(&h[cbuf[s]], 1u);
            float bx = xs[s], by = xs[S_+s], bz = xs[2*S_+s];
            float nn = fmaf(bz, bz, fmaf(by, by, bx*bx));   // proven fma order
            wpts[(size_t)b*S_ + pos] = make_float4(-2.f*bx, -2.f*by, -2.f*bz, nn);
            wsid[(size_t)b*S_ + pos] = (unsigned short)s;
        }
    } else {
        for (int s = t; s < N_; s += 1024) {
            unsigned int pos = atomicAdd(&h[cbuf[s]], 1u);
            wqid[(size_t)b*N_ + pos] = (unsigned short)s;
        }
    }
}

/* ---- 2-D two-pass exact 3-NN + interpolation (8 slots/query) ---------- */
// 2048 blocks x 256 thr; wave = 8 (x,y)-sorted queries x 8 slots.
// PASS 1 (value-only): scan wave-union 3x3 bin rectangle -> slot butterfly
//   -> per-query d3ub -> rad = sqrt(d3ub + 1e-3). !(rr<=64) (sentinel/inf/
//   NaN/huge) -> full-grid flag.
// PASS 2 (u64, fresh accumulators): scan all bins intersecting the square
//   [ax±rad]x[ay±rad] (y-contiguous segment per x-bin, wave-uniform).
// Exactness: pass-1's top-3 lie in the square (|dx|,|dy| <= sqrt(d3ub) <
// rad) so pass 2 holds >=3 real candidates; any unscanned point has
// |dx|>rad or |dy|>rad (bin-edge + clamp argument per axis, as proven for
// the 1-D slab) => dist^2 > d3ub+1e-3 >= final d3 + margin >> fma rounding
// => cannot enter or tie the top-3. u64 composite keeps tie multisets
// exact. idx = sorted position; remapped via wsid at the end.
__global__ __launch_bounds__(256, 4) void knn2d_kernel(
    const float* __restrict__ xyz1,
    const float4* __restrict__ wpts,
    const unsigned short* __restrict__ wsid,
    const unsigned short* __restrict__ wcum,
    const unsigned short* __restrict__ wqid,
    const float* __restrict__ points2,
    float* __restrict__ out)
{
    __shared__ float s_w[3][QBLK];
    __shared__ int   s_idx[3][QBLK];
    __shared__ int   s_oq[QBLK];

    const int b    = blockIdx.x & 7;             // batch-per-XCD swizzle
    const int qblk = blockIdx.x >> 3;
    const int t = threadIdx.x;
    const int wave = t >> 6, wl = t & 63;
    const int qi = wl >> 3, slot = wl & 7;
    const int row = wave * QW + qi;

    const unsigned short* cum = wcum + (size_t)b * CUMP2;
    const int q = wqid[(size_t)b * N_ + qblk * QBLK + row];
    const float* x1 = xyz1 + (size_t)b*3*N_;
    const float ax = x1[q], ay = x1[N_+q], az = x1[2*N_+q];
    const float n1a = fmaf(az, az, fmaf(ay, ay, ax*ax));
    const int qxb = min(NBG-1, max(0, (int)floorf((ax - XMINB)*INVWB)));
    const int qyb = min(NBG-1, max(0, (int)floorf((ay - XMINB)*INVWB)));

    // wave-uniform pass-1 rectangle: union of per-query 3x3 neighborhoods
    int xlo = max(qxb-1, 0), xhi = min(qxb+1, NBG-1);
    int ylo = max(qyb-1, 0), yhi = min(qyb+1, NBG-1);
    #pragma unroll
    for (int off = 1; off < 64; off <<= 1) {
        xlo = min(xlo, __shfl_xor(xlo, off));
        xhi = max(xhi, __shfl_xor(xhi, off));
        ylo = min(ylo, __shfl_xor(ylo, off));
        yhi = max(yhi, __shfl_xor(yhi, off));
    }
    xlo = __builtin_amdgcn_readfirstlane(xlo);
    xhi = __builtin_amdgcn_readfirstlane(xhi);
    ylo = __builtin_amdgcn_readfirstlane(ylo);
    yhi = __builtin_amdgcn_readfirstlane(yhi);

    const float4* pts4 = wpts + (size_t)b * S_;

    // PASS 1: value-only top-3 (per-lane slot partition, disjoint sets)
    float v0 = __builtin_inff(), v1 = __builtin_inff(), v2 = __builtin_inff();
    for (int xb = xlo; xb <= xhi; ++xb) {
        const int s0 = cum[(xb << 5) + ylo];        // wave-uniform scalar
        const int s1 = cum[(xb << 5) + yhi + 1];
        for (int j = s0 + slot; j < s1; j += 8) {
            float4 p = pts4[j];
            float key = fmaf(ax, p.x, fmaf(ay, p.y, fmaf(az, p.z, p.w)));
            ins3v(key, v0, v1, v2);
        }
    }
    // one-shot slot butterfly (disjoint leaf sets -> valid multiset merge)
    #pragma unroll
    for (int off = 1; off < 8; off <<= 1) {
        float s0 = __shfl_xor(v0, off);
        float s1 = __shfl_xor(v1, off);
        float s2 = __shfl_xor(v2, off);
        ins3v(s0, v0, v1, v2);
        ins3v(s1, v0, v1, v2);
        ins3v(s2, v0, v1, v2);
    }
    float rr = v2 + n1a + 1e-3f;
    const bool full = !(rr <= 64.0f);   // sentinel(inf)/NaN/huge -> scan all
    float rad = sqrtf(fmaxf(rr, 0.0f));

    int lxb = full ? 0       : min(NBG-1, max(0, (int)floorf((ax - rad - XMINB)*INVWB)));
    int hxb = full ? NBG-1   : min(NBG-1, max(0, (int)floorf((ax + rad - XMINB)*INVWB)));
    int lyb = full ? 0       : min(NBG-1, max(0, (int)floorf((ay - rad - XMINB)*INVWB)));
    int hyb = full ? NBG-1   : min(NBG-1, max(0, (int)floorf((ay + rad - XMINB)*INVWB)));
    #pragma unroll
    for (int off = 1; off < 64; off <<= 1) {
        lxb = min(lxb, __shfl_xor(lxb, off));
        hxb = max(hxb, __shfl_xor(hxb, off));
        lyb = min(lyb, __shfl_xor(lyb, off));
        hyb = max(hyb, __shfl_xor(hyb, off));
    }
    lxb = __builtin_amdgcn_readfirstlane(lxb);
    hxb = __builtin_amdgcn_readfirstlane(hxb);
    lyb = __builtin_amdgcn_readfirstlane(lyb);
    hyb = __builtin_amdgcn_readfirstlane(hyb);

    // PASS 2: u64 top-3, FRESH accumulators, region segments (disjoint)
    unsigned long long a0 = ~0ull, a1 = ~0ull, a2 = ~0ull;
    for (int xb = lxb; xb <= hxb; ++xb) {
        const int s0 = cum[(xb << 5) + lyb];
        const int s1 = cum[(xb << 5) + hyb + 1];
        for (int j = s0 + slot; j < s1; j += 8) {
            float4 p = pts4[j];
            float key = fmaf(ax, p.x, fmaf(ay, p.y, fmaf(az, p.z, p.w)));
            ins3u64(packkey(key, j), a0, a1, a2);
        }
    }
    // single destructive slot butterfly (disjoint slot classes -> no dups)
    #pragma unroll
    for (int off = 1; off < 8; off <<= 1) {
        unsigned long long t0 = __shfl_xor(a0, off);
        unsigned long long t1 = __shfl_xor(a1, off);
        unsigned long long t2 = __shfl_xor(a2, off);
        ins3u64(t0, a0, a1, a2);
        ins3u64(t1, a0, a1, a2);
        ins3u64(t2, a0, a1, a2);
    }

    // epilogue: weights (proven arithmetic) + sorted-pos -> original id
    if (slot == 0) {
        const unsigned short* sid = wsid + (size_t)b * S_;
        unsigned int sb0 = (unsigned int)(a0 >> 16);
        unsigned int sb1 = (unsigned int)(a1 >> 16);
        unsigned int sb2b = (unsigned int)(a2 >> 16);
        float e0 = __uint_as_float((sb0 & 0x80000000u) ? (sb0 ^ 0x80000000u) : ~sb0);
        float e1 = __uint_as_float((sb1 & 0x80000000u) ? (sb1 ^ 0x80000000u) : ~sb1);
        float e2 = __uint_as_float((sb2b & 0x80000000u) ? (sb2b ^ 0x80000000u) : ~sb2b);
        float r0f = __fdiv_rn(1.0f, __fadd_rn(__fadd_rn(e0, n1a), EPS_));
        float r1f = __fdiv_rn(1.0f, __fadd_rn(__fadd_rn(e1, n1a), EPS_));
        float r2f = __fdiv_rn(1.0f, __fadd_rn(__fadd_rn(e2, n1a), EPS_));
        float rs = __fadd_rn(__fadd_rn(r0f, r1f), r2f);
        s_w[0][row] = __fdiv_rn(r0f, rs);
        s_w[1][row] = __fdiv_rn(r1f, rs);
        s_w[2][row] = __fdiv_rn(r2f, rs);
        s_idx[0][row] = sid[(int)(a0 & 0xFFFFu)];
        s_idx[1][row] = sid[(int)(a1 & 0xFFFFu)];
        s_idx[2][row] = sid[(int)(a2 & 0xFFFFu)];
        s_oq[row] = q;
    }
    __syncthreads();

    // phase C: gather + weighted sum; 32 rows, 4 waves, 64 lanes x float4
    const float* p2 = points2 + (size_t)b * S_ * D_;
    for (int r = wave; r < QBLK; r += 4) {
        float w0 = s_w[0][r], w1 = s_w[1][r], w2 = s_w[2][r];
        float* op = out + ((size_t)b*N_ + s_oq[r]) * D_;
        const float4* f0 = (const float4*)(p2 + (size_t)s_idx[0][r]*D_) + wl;
        const float4* f1 = (const float4*)(p2 + (size_t)s_idx[1][r]*D_) + wl;
        const float4* f2 = (const float4*)(p2 + (size_t)s_idx[2][r]*D_) + wl;
        float4 g0 = *f0, g1 = *f1, g2 = *f2;
        float4 r4;
        r4.x = w0*g0.x + w1*g1.x + w2*g2.x;
        r4.y = w0*g0.y + w1*g1.y + w2*g2.y;
        r4.z = w0*g0.z + w1*g1.z + w2*g2.z;
        r4.w = w0*g0.w + w1*g1.w + w2*g2.w;
        *((float4*)op + wl) = r4;
    }
}

/* ---------------- brute-force fallback (proven R2 path) ------------- */
__global__ __launch_bounds__(NTHR, 8) void fp_brute_kernel(
    const float* __restrict__ xyz1,
    const float* __restrict__ xyz2,
    const float* __restrict__ points2,
    float* __restrict__ out)
{
    __shared__ float s_nn[S_] __attribute__((aligned(16)));
    __shared__ float s_pd[NCH][3][TILE_Q];
    __shared__ int   s_pi[NCH][3][TILE_Q];
    __shared__ float s_w[3][TILE_Q];
    __shared__ int   s_idx[3][TILE_Q];

    const int b  = blockIdx.x & 7;
    const int n0 = (blockIdx.x >> 3) * TILE_Q;
    const int t = threadIdx.x;
    const int wave = t >> 6, lane = t & 63;

    const float* x2 = xyz2 + (size_t)b * 3 * S_;
    for (int s = t; s < S_; s += NTHR) {
        float bx = x2[s], by = x2[S_ + s], bz = x2[2 * S_ + s];
        s_nn[s] = fmaf(bz, bz, fmaf(by, by, bx * bx));
    }
    __syncthreads();

    const int n = n0 + lane;
    const float* x1 = xyz1 + (size_t)b * 3 * N_;
    const float ax = x1[n], ay = x1[N_ + n], az = x1[2 * N_ + n];
    const float ax2 = -2.0f * ax, ay2 = -2.0f * ay, az2 = -2.0f * az;

    float a0 = __builtin_inff(), a1 = __builtin_inff(), a2 = __builtin_inff();
    int ja0 = 0, ja1 = 0, ja2 = 0;
    float c0 = __builtin_inff(), c1 = __builtin_inff(), c2 = __builtin_inff();
    int jc0 = 0, jc1 = 0, jc2 = 0;

    const int wu   = __builtin_amdgcn_readfirstlane(wave);
    const int sbeg = wu * CHUNK;
    const float* bxp = x2;
    const float* byp = x2 + S_;
    const float* bzp = x2 + 2 * S_;
    const float4* nn4 = (const float4*)s_nn;
    const int g0 = sbeg >> 2;
    #pragma unroll 2
    for (int g = 0; g < HALF / 4; ++g) {
        float4 nl = nn4[g0 + g];
        float4 nh = nn4[g0 + (HALF >> 2) + g];
        #pragma unroll
        for (int u = 0; u < 4; ++u) {
            const int sl = sbeg + 4 * g + u;
            const int sh = sl + HALF;
            float kl = fmaf(ax2, bxp[sl],
                       fmaf(ay2, byp[sl], fmaf(az2, bzp[sl], (&nl.x)[u])));
            float kh = fmaf(ax2, bxp[sh],
                       fmaf(ay2, byp[sh], fmaf(az2, bzp[sh], (&nh.x)[u])));
            insert3(kl, sl, a0, a1, a2, ja0, ja1, ja2);
            insert3(kh, sh, c0, c1, c2, jc0, jc1, jc2);
        }
    }
    insert3(c0, jc0, a0, a1, a2, ja0, ja1, ja2);
    insert3(c1, jc1, a0, a1, a2, ja0, ja1, ja2);
    insert3(c2, jc2, a0, a1, a2, ja0, ja1, ja2);

    s_pd[wave][0][lane] = a0; s_pd[wave][1][lane] = a1; s_pd[wave][2][lane] = a2;
    s_pi[wave][0][lane] = ja0; s_pi[wave][1][lane] = ja1; s_pi[wave][2][lane] = ja2;
    __syncthreads();

    if (t < TILE_Q) {
        float e0 = __builtin_inff(), e1 = __builtin_inff(), e2 = __builtin_inff();
        int j0 = 0, j1 = 0, j2 = 0;
        #pragma unroll
        for (int c = 0; c < NCH; ++c)
            #pragma unroll
            for (int k = 0; k < 3; ++k)
                insert3(s_pd[c][k][t], s_pi[c][k][t], e0, e1, e2, j0, j1, j2);
        const int nq = n0 + t;
        float qx = x1[nq], qy = x1[N_ + nq], qz = x1[2 * N_ + nq];
        float n1 = fmaf(qz, qz, fmaf(qy, qy, qx * qx));
        float r0 = __fdiv_rn(1.0f, __fadd_rn(__fadd_rn(e0, n1), EPS_));
        float r1 = __fdiv_rn(1.0f, __fadd_rn(__fadd_rn(e1, n1), EPS_));
        float r2 = __fdiv_rn(1.0f, __fadd_rn(__fadd_rn(e2, n1), EPS_));
        float rs = __fadd_rn(__fadd_rn(r0, r1), r2);
        s_w[0][t] = __fdiv_rn(r0, rs);
        s_w[1][t] = __fdiv_rn(r1, rs);
        s_w[2][t] = __fdiv_rn(r2, rs);
        s_idx[0][t] = j0; s_idx[1][t] = j1; s_idx[2][t] = j2;
    }
    __syncthreads();

    const float* p2 = points2 + (size_t)b * S_ * D_;
    float* op = out + ((size_t)b * N_ + n0) * D_;
    for (int qq = wave; qq < TILE_Q; qq += NCH) {
        float w0 = s_w[0][qq], w1 = s_w[1][qq], w2 = s_w[2][qq];
        const float4* f0 = (const float4*)(p2 + (size_t)s_idx[0][qq] * D_) + lane;
        const float4* f1 = (const float4*)(p2 + (size_t)s_idx[1][qq] * D_) + lane;
        const float4* f2 = (const float4*)(p2 + (size_t)s_idx[2][qq] * D_) + lane;
        float4 v0 = *f0, v1 = *f1, v2 = *f2;
        float4 r;
        r.x = w0 * v0.x + w1 * v1.x + w2 * v2.x;
        r.y = w0 * v0.y + w1 * v1.y + w2 * v2.y;
        r.z = w0 * v0.z + w1 * v1.z + w2 * v2.z;
        r.w = w0 * v0.w + w1 * v1.w + w2 * v2.w;
        *((float4*)(op + (size_t)qq * D_) + lane) = r;
    }
}

extern "C" void kernel_launch(void* const* d_in, const int* in_sizes, int n_in,
                              void* d_out, int out_size, void* d_ws, size_t ws_size,
                              hipStream_t stream) {
    const float* xyz1    = (const float*)d_in[0];
    const float* xyz2    = (const float*)d_in[1];
    // d_in[2] = points1 is unused by the reference output.
    const float* points2 = (const float*)d_in[3];
    float* out = (float*)d_out;

    if (d_ws && ws_size >= (size_t)WS_NEED) {
        float4*         wpts = (float4*)d_ws;
        unsigned short* wsid = (unsigned short*)((char*)d_ws + WS_SID);
        unsigned short* wcum = (unsigned short*)((char*)d_ws + WS_CUM);
        unsigned short* wqid = (unsigned short*)((char*)d_ws + WS_QID);
        prep_sort_kernel<<<dim3(2*B_), dim3(1024), 0, stream>>>(
            xyz1, xyz2, wpts, wsid, wcum, wqid);
        knn2d_kernel<<<dim3(B_ * (N_/QBLK)), dim3(256), 0, stream>>>(
            xyz1, wpts, wsid, wcum, wqid, points2, out);
    } else {
        fp_brute_kernel<<<dim3(B_ * (N_ / TILE_Q)), dim3(NTHR), 0, stream>>>(
            xyz1, xyz2, points2, out);
    }
}

// Round 11
// 167.019 us; speedup vs baseline: 1.1176x; 1.1176x over previous
//
#include <hip/hip_runtime.h>

#define B_ 8
#define N_ 8192
#define S_ 2048
#define D_ 256
#define EPS_ 1e-8f

/* ---------------- 1-D x-sort parameters ---------------- */
#define NBX   256
#define XMIN_ (-4.0f)
#define INVW_ 32.0f            /* bin width 1/32 over [-4,4) */
#define CUMP  258              /* cum array padded to even u16 count */

/* workspace layout (bytes) */
#define WS_SID  (B_*S_*16)                 /* wpts: 262144 */
#define WS_CUM  (WS_SID + B_*S_*2)         /* wsid: +32768 = 294912 */
#define WS_QID  (WS_CUM + B_*CUMP*2)       /* wcum: +4128 = 299040 */
#define WS_NEED (WS_QID + B_*N_*2)         /* wqid: +131072 = 430112 */

#define QW 8                               /* queries per wave (8 slots each) */
#define QBLK 32                            /* queries per 256-thr block */

/* ---------------- brute-force fallback params (proven R2 path) ----- */
#define TILE_Q 64
#define NTHR 512
#define NCH 8
#define CHUNK (S_/NCH)
#define HALF (CHUNK/2)

// Branchless stable top-3 insert (float + index) — brute fallback only.
__device__ __forceinline__ void insert3(float dd, int s,
                                        float& d0, float& d1, float& d2,
                                        int& i0, int& i1, int& i2) {
    bool ca = dd < d0;
    bool cb = dd < d1;
    bool cc = dd < d2;
    int i2n = cb ? i1 : (cc ? s : i2);
    int i1n = ca ? i0 : (cb ? s : i1);
    int i0n = ca ? s : i0;
    d2 = fminf(d2, fmaxf(d1, dd));
    d1 = __builtin_amdgcn_fmed3f(d0, d1, dd);
    d0 = fminf(d0, dd);
    i0 = i0n; i1 = i1n; i2 = i2n;
}

// Top-3 insert on packed u64 composite (sortable(key)<<16 | pos).
// SESSION LEDGER (hardware-measured, do not revisit):
//   - u64 composite @ (256,8), single chain:      knn = 60.0 us  <- THIS
//   - float+index insert (fewer ops):             knn = 72   us  (R8)
//   - two-chain ILP @ (256,4):                    knn = 63.5 us  (R9)
//   - 2-D (x,y) bin pruning (fewer candidates):   knn = 80   us  (R10,
//     fragmented stream -> latency-bound, VALUBusy 28%)
// The 1-D contiguous slab + u64 single chain is the measured optimum.
// MERGE DISCIPLINE (R3): equal composites duplicate; only combine
// DISJOINT candidate sets; never re-reduce an already-merged result.
// Per-lane accumulators stay private (slot classes disjoint); the probe
// merges COPIES into discarded temps; one destructive butterfly at end.
__device__ __forceinline__ void ins3u64(unsigned long long x,
    unsigned long long& d0, unsigned long long& d1, unsigned long long& d2) {
    bool ca = x < d0, cb = x < d1, cc = x < d2;
    d2 = cb ? d1 : (cc ? x : d2);
    d1 = ca ? d0 : (cb ? x : d1);
    d0 = ca ? x : d0;
}

__device__ __forceinline__ unsigned long long packkey(float key, int j) {
    unsigned int kb = __float_as_uint(key);
    unsigned int sb = kb ^ ((unsigned int)((int)kb >> 31) | 0x80000000u);
    return ((unsigned long long)sb << 16) | (unsigned)j;
}

/* ------------- prep: counting-sort candidates by bx, queries by ax ----- */
// (R8-proven: 1024 threads ~3 us vs ~15 at 256.) blocks 0..7: candidates;
// 8..15: queries.
__global__ __launch_bounds__(1024) void prep_sort_kernel(
    const float* __restrict__ xyz1, const float* __restrict__ xyz2,
    float4* __restrict__ wpts, unsigned short* __restrict__ wsid,
    unsigned short* __restrict__ wcum, unsigned short* __restrict__ wqid)
{
    __shared__ unsigned int h[NBX];
    __shared__ unsigned int wsum[4];
    __shared__ unsigned char cbin[N_];
    const int blk = blockIdx.x, t = threadIdx.x, lane = t & 63, wv = t >> 6;

    const bool isq = blk >= B_;
    const int b = isq ? blk - B_ : blk;
    const int cnt = isq ? N_ : S_;
    const float* xs = isq ? (xyz1 + (size_t)b*3*N_) : (xyz2 + (size_t)b*3*S_);

    if (t < NBX) h[t] = 0;
    __syncthreads();
    for (int s = t; s < cnt; s += 1024) {
        float x = xs[s];
        int bin = min(NBX-1, max(0, (int)floorf((x - XMIN_) * INVW_)));
        cbin[s] = (unsigned char)bin;
        atomicAdd(&h[bin], 1u);
    }
    __syncthreads();
    unsigned int v = 0, incl = 0;
    if (t < NBX) {                       // waves 0..3 fully active (uniform)
        v = h[t];
        incl = v;
        #pragma unroll
        for (int off = 1; off < 64; off <<= 1) {
            unsigned int u = __shfl_up(incl, off);
            if (lane >= off) incl += u;
        }
        if (lane == 63) wsum[wv] = incl;
    }
    __syncthreads();
    if (t < NBX) {
        unsigned int base = 0;
        for (int w = 0; w < wv; ++w) base += wsum[w];
        unsigned int excl = base + incl - v;
        h[t] = excl;
        if (!isq) {
            unsigned short* cum = wcum + (size_t)b * CUMP;
            cum[t] = (unsigned short)excl;
            if (t == 0) { cum[NBX] = (unsigned short)S_; cum[NBX+1] = (unsigned short)S_; }
        }
    }
    __syncthreads();
    if (!isq) {
        for (int s = t; s < S_; s += 1024) {
            unsigned int pos = atomicAdd(&h[cbin[s]], 1u);
            float bx = xs[s], by = xs[S_+s], bz = xs[2*S_+s];
            float nn = fmaf(bz, bz, fmaf(by, by, bx*bx));   // proven fma order
            wpts[(size_t)b*S_ + pos] = make_float4(-2.f*bx, -2.f*by, -2.f*bz, nn);
            wsid[(size_t)b*S_ + pos] = (unsigned short)s;
        }
    } else {
        for (int s = t; s < N_; s += 1024) {
            unsigned int pos = atomicAdd(&h[cbin[s]], 1u);
            wqid[(size_t)b*N_ + pos] = (unsigned short)s;
        }
    }
}

/* ------ one-shot slab exact 3-NN + interpolation (8 slots/query) ------- */
// (R7-proven kernel, verbatim — measured 60.0 us.) 2048 blocks x 256 thr.
// Wave = 8 sorted queries x 8 slots; lane = qi*8 + slot. Per scan iter the
// 8 slots read 8 CONSECUTIVE float4s (128 contiguous bytes, broadcast to
// the 8 qi-groups). Schedule: scan(window +-128 rank) -> probe d3ub
// (temp copies, discarded) -> slab = [cum[bin(ax-rad)], cum[bin(ax+rad)+1])
// union over wave -> scan(slab \ window) -> single destructive slot merge.
// Exactness: unscanned candidate => bin outside slab => |bx-ax| > rad =>
// dist^2 > d3ub + 1e-3 (margin >> fma rounding) => cannot enter or tie
// the top-3. idx = sorted position; remapped via wsid at the end.
__global__ __launch_bounds__(256, 8) void knn8_kernel(
    const float* __restrict__ xyz1,
    const float4* __restrict__ wpts,
    const unsigned short* __restrict__ wsid,
    const unsigned short* __restrict__ wcum,
    const unsigned short* __restrict__ wqid,
    const float* __restrict__ points2,
    float* __restrict__ out)
{
    __shared__ float s_w[3][QBLK];
    __shared__ int   s_idx[3][QBLK];
    __shared__ int   s_oq[QBLK];

    const int b    = blockIdx.x & 7;             // batch-per-XCD swizzle
    const int qblk = blockIdx.x >> 3;
    const int t = threadIdx.x;
    const int wave = t >> 6, wl = t & 63;
    const int qi = wl >> 3, slot = wl & 7;
    const int row = wave * QW + qi;              // 0..31 within block

    const unsigned short* cum = wcum + (size_t)b * CUMP;
    const int q = wqid[(size_t)b * N_ + qblk * QBLK + row];
    const float* x1 = xyz1 + (size_t)b*3*N_;
    const float ax = x1[q], ay = x1[N_+q], az = x1[2*N_+q];
    const float n1a = fmaf(az, az, fmaf(ay, ay, ax*ax));
    const int qbin = min(NBX-1, max(0, (int)floorf((ax - XMIN_)*INVW_)));
    const int cq = cum[qbin];

    // wave-uniform window around this wave's 8 queries
    int cmin = cq, cmax = cq;
    #pragma unroll
    for (int off = 1; off < 64; off <<= 1) {
        cmin = min(cmin, __shfl_xor(cmin, off));
        cmax = max(cmax, __shfl_xor(cmax, off));
    }
    const int wlo = __builtin_amdgcn_readfirstlane(max(cmin - 128, 0));
    const int whi = __builtin_amdgcn_readfirstlane(min(cmax + 128, S_));

    const float4* pts4 = wpts + (size_t)b * S_;
    unsigned long long m0 = ~0ull, m1 = ~0ull, m2 = ~0ull;   // sentinels

    auto scan = [&](int j0, int j1) {
        #pragma unroll 4
        for (int j = j0 + slot; j < j1; j += 8) {
            float4 p = pts4[j];
            float key = fmaf(ax, p.x, fmaf(ay, p.y, fmaf(az, p.z, p.w)));
            ins3u64(packkey(key, j), m0, m1, m2);
        }
    };

    scan(wlo, whi);          // >=128 candidates seen by every query

    // ONE non-destructive probe: per-query d3 upper bound (temp copies,
    // xor 1/2/4 spans the 8 slots; discarded after rad)
    unsigned long long r0 = m0, r1 = m1, r2 = m2;
    #pragma unroll
    for (int off = 1; off < 8; off <<= 1) {
        unsigned long long t0 = __shfl_xor(r0, off);
        unsigned long long t1 = __shfl_xor(r1, off);
        unsigned long long t2 = __shfl_xor(r2, off);
        ins3u64(t0, r0, r1, r2);
        ins3u64(t1, r0, r1, r2);
        ins3u64(t2, r0, r1, r2);
    }
    unsigned int sb2 = (unsigned int)(r2 >> 16);
    unsigned int kb2 = (sb2 & 0x80000000u) ? (sb2 ^ 0x80000000u) : ~sb2;
    float rad = sqrtf(fmaxf(__uint_as_float(kb2) + n1a + 1e-3f, 0.0f));
    int lob = min(NBX-1, max(0, (int)floorf((ax - rad - XMIN_)*INVW_)));
    int hib = min(NBX-1, max(0, (int)floorf((ax + rad - XMIN_)*INVW_)));
    int lo = cum[lob], hi = cum[hib + 1];

    // wave-uniform slab union
    int ulo = lo, uhi = hi;
    #pragma unroll
    for (int off = 1; off < 64; off <<= 1) {
        ulo = min(ulo, __shfl_xor(ulo, off));
        uhi = max(uhi, __shfl_xor(uhi, off));
    }
    ulo = __builtin_amdgcn_readfirstlane(ulo);
    uhi = __builtin_amdgcn_readfirstlane(uhi);

    // disjoint extensions (each j visited exactly once per query)
    scan(ulo, wlo);
    scan(whi, uhi);

    // single destructive slot butterfly (disjoint slot classes -> no dups)
    #pragma unroll
    for (int off = 1; off < 8; off <<= 1) {
        unsigned long long t0 = __shfl_xor(m0, off);
        unsigned long long t1 = __shfl_xor(m1, off);
        unsigned long long t2 = __shfl_xor(m2, off);
        ins3u64(t0, m0, m1, m2);
        ins3u64(t1, m0, m1, m2);
        ins3u64(t2, m0, m1, m2);
    }

    // epilogue: weights (proven arithmetic) + sorted-pos -> original id
    if (slot == 0) {
        const unsigned short* sid = wsid + (size_t)b * S_;
        unsigned int sb0 = (unsigned int)(m0 >> 16);
        unsigned int sb1 = (unsigned int)(m1 >> 16);
        unsigned int sb2b = (unsigned int)(m2 >> 16);
        float e0 = __uint_as_float((sb0 & 0x80000000u) ? (sb0 ^ 0x80000000u) : ~sb0);
        float e1 = __uint_as_float((sb1 & 0x80000000u) ? (sb1 ^ 0x80000000u) : ~sb1);
        float e2 = __uint_as_float((sb2b & 0x80000000u) ? (sb2b ^ 0x80000000u) : ~sb2b);
        float r0f = __fdiv_rn(1.0f, __fadd_rn(__fadd_rn(e0, n1a), EPS_));
        float r1f = __fdiv_rn(1.0f, __fadd_rn(__fadd_rn(e1, n1a), EPS_));
        float r2f = __fdiv_rn(1.0f, __fadd_rn(__fadd_rn(e2, n1a), EPS_));
        float rs = __fadd_rn(__fadd_rn(r0f, r1f), r2f);
        s_w[0][row] = __fdiv_rn(r0f, rs);
        s_w[1][row] = __fdiv_rn(r1f, rs);
        s_w[2][row] = __fdiv_rn(r2f, rs);
        s_idx[0][row] = sid[(int)(m0 & 0xFFFFu)];
        s_idx[1][row] = sid[(int)(m1 & 0xFFFFu)];
        s_idx[2][row] = sid[(int)(m2 & 0xFFFFu)];
        s_oq[row] = q;
    }
    __syncthreads();

    // phase C: gather + weighted sum; 32 rows, 4 waves, 64 lanes x float4
    const float* p2 = points2 + (size_t)b * S_ * D_;
    for (int r = wave; r < QBLK; r += 4) {
        float w0 = s_w[0][r], w1 = s_w[1][r], w2 = s_w[2][r];
        float* op = out + ((size_t)b*N_ + s_oq[r]) * D_;
        const float4* f0 = (const float4*)(p2 + (size_t)s_idx[0][r]*D_) + wl;
        const float4* f1 = (const float4*)(p2 + (size_t)s_idx[1][r]*D_) + wl;
        const float4* f2 = (const float4*)(p2 + (size_t)s_idx[2][r]*D_) + wl;
        float4 v0 = *f0, v1 = *f1, v2v = *f2;
        float4 r4;
        r4.x = w0*v0.x + w1*v1.x + w2*v2v.x;
        r4.y = w0*v0.y + w1*v1.y + w2*v2v.y;
        r4.z = w0*v0.z + w1*v1.z + w2*v2v.z;
        r4.w = w0*v0.w + w1*v1.w + w2*v2v.w;
        *((float4*)op + wl) = r4;
    }
}

/* ---------------- brute-force fallback (proven R2 path) ------------- */
__global__ __launch_bounds__(NTHR, 8) void fp_brute_kernel(
    const float* __restrict__ xyz1,
    const float* __restrict__ xyz2,
    const float* __restrict__ points2,
    float* __restrict__ out)
{
    __shared__ float s_nn[S_] __attribute__((aligned(16)));
    __shared__ float s_pd[NCH][3][TILE_Q];
    __shared__ int   s_pi[NCH][3][TILE_Q];
    __shared__ float s_w[3][TILE_Q];
    __shared__ int   s_idx[3][TILE_Q];

    const int b  = blockIdx.x & 7;
    const int n0 = (blockIdx.x >> 3) * TILE_Q;
    const int t = threadIdx.x;
    const int wave = t >> 6, lane = t & 63;

    const float* x2 = xyz2 + (size_t)b * 3 * S_;
    for (int s = t; s < S_; s += NTHR) {
        float bx = x2[s], by = x2[S_ + s], bz = x2[2 * S_ + s];
        s_nn[s] = fmaf(bz, bz, fmaf(by, by, bx * bx));
    }
    __syncthreads();

    const int n = n0 + lane;
    const float* x1 = xyz1 + (size_t)b * 3 * N_;
    const float ax = x1[n], ay = x1[N_ + n], az = x1[2 * N_ + n];
    const float ax2 = -2.0f * ax, ay2 = -2.0f * ay, az2 = -2.0f * az;

    float a0 = __builtin_inff(), a1 = __builtin_inff(), a2 = __builtin_inff();
    int ja0 = 0, ja1 = 0, ja2 = 0;
    float c0 = __builtin_inff(), c1 = __builtin_inff(), c2 = __builtin_inff();
    int jc0 = 0, jc1 = 0, jc2 = 0;

    const int wu   = __builtin_amdgcn_readfirstlane(wave);
    const int sbeg = wu * CHUNK;
    const float* bxp = x2;
    const float* byp = x2 + S_;
    const float* bzp = x2 + 2 * S_;
    const float4* nn4 = (const float4*)s_nn;
    const int g0 = sbeg >> 2;
    #pragma unroll 2
    for (int g = 0; g < HALF / 4; ++g) {
        float4 nl = nn4[g0 + g];
        float4 nh = nn4[g0 + (HALF >> 2) + g];
        #pragma unroll
        for (int u = 0; u < 4; ++u) {
            const int sl = sbeg + 4 * g + u;
            const int sh = sl + HALF;
            float kl = fmaf(ax2, bxp[sl],
                       fmaf(ay2, byp[sl], fmaf(az2, bzp[sl], (&nl.x)[u])));
            float kh = fmaf(ax2, bxp[sh],
                       fmaf(ay2, byp[sh], fmaf(az2, bzp[sh], (&nh.x)[u])));
            insert3(kl, sl, a0, a1, a2, ja0, ja1, ja2);
            insert3(kh, sh, c0, c1, c2, jc0, jc1, jc2);
        }
    }
    insert3(c0, jc0, a0, a1, a2, ja0, ja1, ja2);
    insert3(c1, jc1, a0, a1, a2, ja0, ja1, ja2);
    insert3(c2, jc2, a0, a1, a2, ja0, ja1, ja2);

    s_pd[wave][0][lane] = a0; s_pd[wave][1][lane] = a1; s_pd[wave][2][lane] = a2;
    s_pi[wave][0][lane] = ja0; s_pi[wave][1][lane] = ja1; s_pi[wave][2][lane] = ja2;
    __syncthreads();

    if (t < TILE_Q) {
        float e0 = __builtin_inff(), e1 = __builtin_inff(), e2 = __builtin_inff();
        int j0 = 0, j1 = 0, j2 = 0;
        #pragma unroll
        for (int c = 0; c < NCH; ++c)
            #pragma unroll
            for (int k = 0; k < 3; ++k)
                insert3(s_pd[c][k][t], s_pi[c][k][t], e0, e1, e2, j0, j1, j2);
        const int nq = n0 + t;
        float qx = x1[nq], qy = x1[N_ + nq], qz = x1[2 * N_ + nq];
        float n1 = fmaf(qz, qz, fmaf(qy, qy, qx * qx));
        float r0 = __fdiv_rn(1.0f, __fadd_rn(__fadd_rn(e0, n1), EPS_));
        float r1 = __fdiv_rn(1.0f, __fadd_rn(__fadd_rn(e1, n1), EPS_));
        float r2 = __fdiv_rn(1.0f, __fadd_rn(__fadd_rn(e2, n1), EPS_));
        float rs = __fadd_rn(__fadd_rn(r0, r1), r2);
        s_w[0][t] = __fdiv_rn(r0, rs);
        s_w[1][t] = __fdiv_rn(r1, rs);
        s_w[2][t] = __fdiv_rn(r2, rs);
        s_idx[0][t] = j0; s_idx[1][t] = j1; s_idx[2][t] = j2;
    }
    __syncthreads();

    const float* p2 = points2 + (size_t)b * S_ * D_;
    float* op = out + ((size_t)b * N_ + n0) * D_;
    for (int qq = wave; qq < TILE_Q; qq += NCH) {
        float w0 = s_w[0][qq], w1 = s_w[1][qq], w2 = s_w[2][qq];
        const float4* f0 = (const float4*)(p2 + (size_t)s_idx[0][qq] * D_) + lane;
        const float4* f1 = (const float4*)(p2 + (size_t)s_idx[1][qq] * D_) + lane;
        const float4* f2 = (const float4*)(p2 + (size_t)s_idx[2][qq] * D_) + lane;
        float4 v0 = *f0, v1 = *f1, v2 = *f2;
        float4 r;
        r.x = w0 * v0.x + w1 * v1.x + w2 * v2.x;
        r.y = w0 * v0.y + w1 * v1.y + w2 * v2.y;
        r.z = w0 * v0.z + w1 * v1.z + w2 * v2.z;
        r.w = w0 * v0.w + w1 * v1.w + w2 * v2.w;
        *((float4*)(op + (size_t)qq * D_) + lane) = r;
    }
}

extern "C" void kernel_launch(void* const* d_in, const int* in_sizes, int n_in,
                              void* d_out, int out_size, void* d_ws, size_t ws_size,
                              hipStream_t stream) {
    const float* xyz1    = (const float*)d_in[0];
    const float* xyz2    = (const float*)d_in[1];
    // d_in[2] = points1 is unused by the reference output.
    const float* points2 = (const float*)d_in[3];
    float* out = (float*)d_out;

    if (d_ws && ws_size >= (size_t)WS_NEED) {
        float4*         wpts = (float4*)d_ws;
        unsigned short* wsid = (unsigned short*)((char*)d_ws + WS_SID);
        unsigned short* wcum = (unsigned short*)((char*)d_ws + WS_CUM);
        unsigned short* wqid = (unsigned short*)((char*)d_ws + WS_QID);
        prep_sort_kernel<<<dim3(2*B_), dim3(1024), 0, stream>>>(
            xyz1, xyz2, wpts, wsid, wcum, wqid);
        knn8_kernel<<<dim3(B_ * (N_/QBLK)), dim3(256), 0, stream>>>(
            xyz1, wpts, wsid, wcum, wqid, points2, out);
    } else {
        fp_brute_kernel<<<dim3(B_ * (N_ / TILE_Q)), dim3(NTHR), 0, stream>>>(
            xyz1, xyz2, points2, out);
    }
}